// Round 1
// baseline (488.257 us; speedup 1.0000x reference)
//
#include <hip/hip_runtime.h>

#define DEV static __device__ __forceinline__

constexpr int Bn = 32, Tn = 1024, Vn = 1024, Ln = 100, Sn = 2 * Ln + 1; // S=201
constexpr float NEGF = -1e30f;

DEV float wave_max(float m) {
    #pragma unroll
    for (int off = 32; off; off >>= 1) m = fmaxf(m, __shfl_xor(m, off));
    return m;
}
DEV float wave_sum(float s) {
    #pragma unroll
    for (int off = 32; off; off >>= 1) s += __shfl_xor(s, off);
    return s;
}
DEV float ladd2(float a, float b) {
    float m = fmaxf(a, b);
    return m + __logf(__expf(a - m) + __expf(b - m));
}
DEV float ladd3(float a, float b, float c) {
    float m = fmaxf(fmaxf(a, b), c);
    return m + __logf(__expf(a - m) + __expf(b - m) + __expf(c - m));
}

// Kernel 1: per (b,t) row -> logsumexp, then emit lp_ext[b,t,s] = logits[b,t,ext[s]] - lse
// lp_ext layout: [B, T, 256] floats (256 = 4 states per lane * 64 lanes), s>=201 slots hold
// the blank value (never consumed by active states).
__global__ __launch_bounds__(256) void pre_kernel(const int* __restrict__ targets,
                                                  const float* __restrict__ logits,
                                                  float4* __restrict__ lp_ext) {
    __shared__ float rows[4][Vn];            // 16 KB: one staged row per wave
    const int wid  = threadIdx.x >> 6;
    const int lane = threadIdx.x & 63;
    const int row  = blockIdx.x * 4 + wid;   // row = b*Tn + t  (4 rows/block, same b)
    const int b    = row >> 10;

    const float4* rp = (const float4*)(logits + (size_t)row * Vn);
    float4 v[4];
    #pragma unroll
    for (int k = 0; k < 4; k++) v[k] = rp[k * 64 + lane];

    float m = -3.4e38f;
    #pragma unroll
    for (int k = 0; k < 4; k++)
        m = fmaxf(m, fmaxf(fmaxf(v[k].x, v[k].y), fmaxf(v[k].z, v[k].w)));
    m = wave_max(m);

    float s = 0.f;
    #pragma unroll
    for (int k = 0; k < 4; k++)
        s += __expf(v[k].x - m) + __expf(v[k].y - m) + __expf(v[k].z - m) + __expf(v[k].w - m);
    s = wave_sum(s);
    const float lse = m + __logf(s);

    // stage the row in LDS (same-wave write->read: DS ops are in-order per wave)
    float4* lr4 = (float4*)rows[wid];
    #pragma unroll
    for (int k = 0; k < 4; k++) lr4[k * 64 + lane] = v[k];

    const int* tgp = targets + b * Ln;
    float o[4];
    #pragma unroll
    for (int j = 0; j < 4; j++) {
        int sidx = 4 * lane + j;
        // ext[s]: odd s -> targets[(s-1)/2], else (and s>=S) -> blank = V-1
        int ei = ((sidx & 1) && sidx < Sn) ? tgp[sidx >> 1] : (Vn - 1);
        o[j] = rows[wid][ei] - lse;
    }
    lp_ext[(size_t)row * 64 + lane] = make_float4(o[0], o[1], o[2], o[3]);
}

// Kernel 2: CTC forward recursion. One wave per batch element; lane holds states
// s = 4*lane .. 4*lane+3 (256 >= S=201; inactive states stay ~NEG and never feed back).
__global__ __launch_bounds__(64) void ctc_kernel(const int* __restrict__ targets,
                                                 const float4* __restrict__ lp_ext,
                                                 float* __restrict__ loss) {
    const int b    = blockIdx.x;
    const int lane = threadIdx.x;

    __shared__ int tg[Ln];
    if (lane < Ln / 2) ((int2*)tg)[lane] = ((const int2*)(targets + b * Ln))[lane];
    __syncthreads();

    // skip allowed only at odd s>=3 where the two surrounding labels differ.
    // s parity == register-index parity: j=0,2 (even s) never skip.
    bool sk1 = false, sk3 = false;
    {
        int s1 = 4 * lane + 1, s3 = 4 * lane + 3;
        if (s1 >= 3 && s1 < Sn) sk1 = (tg[s1 >> 1] != tg[(s1 - 3) >> 1]);
        if (s3 >= 3 && s3 < Sn) sk3 = (tg[s3 >> 1] != tg[(s3 - 3) >> 1]);
    }

    const float4* lpb = lp_ext + (size_t)b * Tn * 64;
    float4 lp0 = lpb[lane];   // t = 0
    float a0 = NEGF, a1 = NEGF, a2 = NEGF, a3 = NEGF;
    if (lane == 0) { a0 = lp0.x; a1 = lp0.y; }   // alpha0[0], alpha0[1]

    auto step = [&](float4 lp) {
        float pm1 = __shfl_up(a3, 1);   // alpha[s-1] for local s0
        float pm2 = __shfl_up(a2, 1);   // alpha[s-2] for local s0
        if (lane == 0) { pm1 = NEGF; pm2 = NEGF; }
        float n0 = ladd2(a0, pm1);                       // even s: no skip
        float n1 = ladd3(a1, a0, sk1 ? pm1 : NEGF);
        float n2 = ladd2(a2, a1);                        // even s: no skip
        float n3 = ladd3(a3, a2, sk3 ? a1 : NEGF);
        a0 = n0 + lp.x; a1 = n1 + lp.y; a2 = n2 + lp.z; a3 = n3 + lp.w;
    };

    // depth-8 float4 ring prefetch; lp_ext padded so t+8 up to 1024 is safe to touch.
    float4 buf[8];
    #pragma unroll
    for (int u = 0; u < 8; u++) buf[u] = lpb[(size_t)(1 + u) * 64 + lane];
    int t = 1;
    for (int c = 0; c < 127; c++) {          // 127*8 = 1016 steps: t = 1..1016
        #pragma unroll
        for (int u = 0; u < 8; u++) {
            float4 cur = buf[u];
            buf[u] = lpb[(size_t)(t + 8) * 64 + lane];   // prefetch (max index t=1024, padded)
            step(cur);
            t++;
        }
    }
    #pragma unroll
    for (int u = 0; u < 7; u++) step(buf[u]);  // t = 1017..1023

    float vS1 = __shfl(a0, 50);   // s = 200  (lane 50, j=0)
    float vS2 = __shfl(a3, 49);   // s = 199  (lane 49, j=3)
    if (lane == 0) loss[b] = -ladd2(vS1, vS2);
}

// Kernel 3: mean over B losses -> scalar (plain store; d_out is re-poisoned each call).
__global__ __launch_bounds__(64) void mean_kernel(const float* __restrict__ loss,
                                                  float* __restrict__ out) {
    int lane = threadIdx.x;
    float v = (lane < Bn) ? loss[lane] : 0.f;
    #pragma unroll
    for (int off = 32; off; off >>= 1) v += __shfl_xor(v, off);
    if (lane == 0) out[0] = v * (1.0f / Bn);
}

extern "C" void kernel_launch(void* const* d_in, const int* in_sizes, int n_in,
                              void* d_out, int out_size, void* d_ws, size_t ws_size,
                              hipStream_t stream) {
    const int*   targets = (const int*)d_in[0];
    const float* logits  = (const float*)d_in[1];

    // ws layout: lp_ext [B*T*64 float4 = 33.55 MB] + 4 KB prefetch pad + loss[32]
    float4* lp_ext = (float4*)d_ws;
    float*  loss   = (float*)((char*)d_ws + (size_t)Bn * Tn * 64 * sizeof(float4) + 4096);

    pre_kernel<<<Bn * Tn / 4, 256, 0, stream>>>(targets, logits, lp_ext);
    ctc_kernel<<<Bn, 64, 0, stream>>>(targets, lp_ext, loss);
    mean_kernel<<<1, 64, 0, stream>>>(loss, (float*)d_out);
}

// Round 2
// 323.065 us; speedup vs baseline: 1.5113x; 1.5113x over previous
//
#include <hip/hip_runtime.h>

#define DEV static __device__ __forceinline__

constexpr int Bn = 32, Tn = 1024, Vn = 1024, Ln = 100, Sn = 2 * Ln + 1; // S=201
constexpr float NEGF   = -1e30f;
constexpr float LN2F   = 0.6931471805599453f;
constexpr float INVLN2 = 1.4426950408889634f;
constexpr int   TILE   = 32;          // timesteps per LDS tile (32 * 1 KB = 32 KB)

typedef const __attribute__((address_space(1))) unsigned int* as1_u32p;
typedef __attribute__((address_space(3))) unsigned int*       as3_u32p;

// async global->LDS DMA, 16 B per lane, lands at lds_base + lane*16 (wave-uniform base)
DEV void async16(const float* g, float* l) {
    __builtin_amdgcn_global_load_lds((as1_u32p)g, (as3_u32p)l, 16, 0, 0);
}

DEV float wave_max(float m) {
    #pragma unroll
    for (int off = 32; off; off >>= 1) m = fmaxf(m, __shfl_xor(m, off));
    return m;
}
DEV float wave_sum(float s) {
    #pragma unroll
    for (int off = 32; off; off >>= 1) s += __shfl_xor(s, off);
    return s;
}

// log2-domain logaddexp with the per-step lp folded into the (off-chain) max term:
// result = (m + lp) + log2(sum 2^(x-m))
DEV float l2add2(float a, float b, float lp) {
    float m = fmaxf(a, b);
    float r = __builtin_amdgcn_logf(__builtin_amdgcn_exp2f(a - m) +
                                    __builtin_amdgcn_exp2f(b - m));
    return (m + lp) + r;
}
DEV float l2add3(float a, float b, float c, float lp) {
    float m = fmaxf(fmaxf(a, b), c);   // -> v_max3_f32
    float r = __builtin_amdgcn_logf(__builtin_amdgcn_exp2f(a - m) +
                                    __builtin_amdgcn_exp2f(b - m) +
                                    __builtin_amdgcn_exp2f(c - m));
    return (m + lp) + r;
}

// Kernel 1: one (b,t) row per 256-thread block.
// lp_ext[row*256 + s] = (logits[row, ext[s]] - lse(row)) * INVLN2   (log2 domain)
__global__ __launch_bounds__(256) void pre_kernel(const int* __restrict__ targets,
                                                  const float* __restrict__ logits,
                                                  float* __restrict__ lp_ext) {
    __shared__ float row[Vn];     // 4 KB
    __shared__ float red[8];
    const int t    = threadIdx.x;
    const int lane = t & 63;
    const int wid  = t >> 6;
    const int rid  = blockIdx.x;          // b*Tn + time
    const int b    = rid >> 10;

    float4 v = ((const float4*)(logits + (size_t)rid * Vn))[t];
    ((float4*)row)[t] = v;

    float m = fmaxf(fmaxf(v.x, v.y), fmaxf(v.z, v.w));
    m = wave_max(m);
    if (lane == 0) red[wid] = m;
    __syncthreads();
    m = fmaxf(fmaxf(red[0], red[1]), fmaxf(red[2], red[3]));

    float e = __expf(v.x - m) + __expf(v.y - m) + __expf(v.z - m) + __expf(v.w - m);
    e = wave_sum(e);
    if (lane == 0) red[4 + wid] = e;
    __syncthreads();
    float s = (red[4] + red[5]) + (red[6] + red[7]);
    const float lse = m + __logf(s);

    // state t: ext[t] = odd && t<S ? targets[t>>1] : blank(V-1)
    int ei = ((t & 1) && t < Sn) ? targets[b * Ln + (t >> 1)] : (Vn - 1);
    lp_ext[(size_t)rid * 256 + t] = (row[ei] - lse) * INVLN2;
}

// Kernel 2: CTC forward recursion, one wave per batch element.
// Lane holds states 4*lane .. 4*lane+3; lp tiles staged via global_load_lds.
__global__ __launch_bounds__(64) void ctc_kernel(const int* __restrict__ targets,
                                                 const float* __restrict__ lp_ext,
                                                 float* __restrict__ loss) {
    __shared__ float tile[2][TILE * 256];   // 64 KB exactly
    const int b    = blockIdx.x;
    const int lane = threadIdx.x;

    // skip flags (odd states only; even-register states never skip)
    bool sk1 = false, sk3 = false;
    {
        const int* tg = targets + b * Ln;
        int s1 = 4 * lane + 1, s3 = 4 * lane + 3;
        if (s1 >= 3 && s1 < Sn) sk1 = (tg[s1 >> 1] != tg[(s1 - 3) >> 1]);
        if (s3 >= 3 && s3 < Sn) sk3 = (tg[s3 >> 1] != tg[(s3 - 3) >> 1]);
    }

    const float* gb = lp_ext + (size_t)b * Tn * 256;

    // stage tiles 0 and 1
    #pragma unroll
    for (int u = 0; u < TILE; u++)
        async16(gb + (size_t)u * 256 + lane * 4, &tile[0][u * 256]);
    #pragma unroll
    for (int u = 0; u < TILE; u++)
        async16(gb + (size_t)(TILE + u) * 256 + lane * 4, &tile[1][u * 256]);

    // virtual alpha_{-1}: lane0 a0 = 0 (log2 of 1), everything else NEG.
    // Then 1024 uniform steps produce exactly alpha_{T-1}.
    float a0 = (lane == 0) ? 0.0f : NEGF, a1 = NEGF, a2 = NEGF, a3 = NEGF;

    const int nt = Tn / TILE;   // 32 tiles
    for (int tb = 0; tb < nt; tb++) {
        const float* cur = tile[tb & 1];
        #pragma unroll
        for (int u = 0; u < TILE; u++) {
            const float4 lp = ((const float4*)(cur + u * 256))[lane];
            float pm1 = __shfl_up(a3, 1);           // alpha[s-1] for local s0
            pm1 = (lane == 0) ? NEGF : pm1;
            float n0 = l2add2(a0, pm1, lp.x);                       // even s: no skip
            float n1 = l2add3(a1, a0, sk1 ? pm1 : NEGF, lp.y);
            float n2 = l2add2(a2, a1, lp.z);                        // even s: no skip
            float n3 = l2add3(a3, a2, sk3 ? a1 : NEGF, lp.w);
            a0 = n0; a1 = n1; a2 = n2; a3 = n3;
        }
        if (tb + 2 < nt) {
            float* nxt = tile[tb & 1];
            const float* gn = gb + (size_t)(tb + 2) * TILE * 256;
            #pragma unroll
            for (int u = 0; u < TILE; u++)
                async16(gn + (size_t)u * 256 + lane * 4, &nxt[u * 256]);
        }
    }

    float vS1 = __shfl(a0, 50);   // s = 200 (lane 50, j=0)
    float vS2 = __shfl(a3, 49);   // s = 199 (lane 49, j=3)
    if (lane == 0) loss[b] = -LN2F * l2add2(vS1, vS2, 0.0f);
}

// Kernel 3: mean over B losses -> scalar.
__global__ __launch_bounds__(64) void mean_kernel(const float* __restrict__ loss,
                                                  float* __restrict__ out) {
    int lane = threadIdx.x;
    float v = (lane < Bn) ? loss[lane] : 0.f;
    #pragma unroll
    for (int off = 32; off; off >>= 1) v += __shfl_xor(v, off);
    if (lane == 0) out[0] = v * (1.0f / Bn);
}

extern "C" void kernel_launch(void* const* d_in, const int* in_sizes, int n_in,
                              void* d_out, int out_size, void* d_ws, size_t ws_size,
                              hipStream_t stream) {
    const int*   targets = (const int*)d_in[0];
    const float* logits  = (const float*)d_in[1];

    // ws: lp_ext [B*T*256 floats = 33.55 MB] + loss[32]
    float* lp_ext = (float*)d_ws;
    float* loss   = (float*)((char*)d_ws + (size_t)Bn * Tn * 256 * sizeof(float) + 4096);

    pre_kernel<<<Bn * Tn, 256, 0, stream>>>(targets, logits, lp_ext);
    ctc_kernel<<<Bn, 64, 0, stream>>>(targets, lp_ext, loss);
    mean_kernel<<<1, 64, 0, stream>>>(loss, (float*)d_out);
}

// Round 4
// 266.785 us; speedup vs baseline: 1.8302x; 1.2110x over previous
//
#include <hip/hip_runtime.h>
#include <math.h>

#define DEV static __device__ __forceinline__

constexpr int Bn = 32, Tn = 1024, Vn = 1024, Ln = 100, Sn = 2 * Ln + 1; // S=201
constexpr float LN2F = 0.6931471805599453f;
constexpr int   TILE = 32;          // timesteps per LDS tile (32 * 1 KB = 32 KB)

typedef const __attribute__((address_space(1))) unsigned int* as1_u32p;
typedef __attribute__((address_space(3))) unsigned int*       as3_u32p;

// async global->LDS DMA, 16 B per lane, lands at lds_base + lane*16 (wave-uniform base)
DEV void async16(const float* g, float* l) {
    __builtin_amdgcn_global_load_lds((as1_u32p)g, (as3_u32p)l, 16, 0, 0);
}
// explicit DMA-arrival fences (only async16 contributes vmcnt inside the K-loop)
#define WAITVM32() asm volatile("s_waitcnt vmcnt(32)" ::: "memory")
#define WAITVM0()  asm volatile("s_waitcnt vmcnt(0)"  ::: "memory")

DEV float wave_max(float m) {
    #pragma unroll
    for (int off = 32; off; off >>= 1) m = fmaxf(m, __shfl_xor(m, off));
    return m;
}
DEV float wave_sum(float s) {
    #pragma unroll
    for (int off = 32; off; off >>= 1) s += __shfl_xor(s, off);
    return s;
}

// Kernel 1: two (b,t) rows per 256-thread block (2 independent loads -> MLP=2).
// Emits PROBABILITIES: lp_ext[row*256 + s] = exp(logits[row, ext[s]] - lse(row)).
__global__ __launch_bounds__(256) void pre_kernel(const int* __restrict__ targets,
                                                  const float* __restrict__ logits,
                                                  float* __restrict__ lp_ext) {
    __shared__ float rows[2][Vn];     // 8 KB
    __shared__ float red[2][8];
    const int t    = threadIdx.x;
    const int lane = t & 63;
    const int wid  = t >> 6;
    const int r0   = blockIdx.x * 2;      // rows r0, r0+1 share the same b (Tn even)
    const int b    = r0 >> 10;

    float4 v0 = ((const float4*)(logits + (size_t)r0 * Vn))[t];
    float4 v1 = ((const float4*)(logits + (size_t)(r0 + 1) * Vn))[t];
    ((float4*)rows[0])[t] = v0;
    ((float4*)rows[1])[t] = v1;

    float m0 = fmaxf(fmaxf(v0.x, v0.y), fmaxf(v0.z, v0.w));
    float m1 = fmaxf(fmaxf(v1.x, v1.y), fmaxf(v1.z, v1.w));
    m0 = wave_max(m0); m1 = wave_max(m1);
    if (lane == 0) { red[0][wid] = m0; red[1][wid] = m1; }
    __syncthreads();
    m0 = fmaxf(fmaxf(red[0][0], red[0][1]), fmaxf(red[0][2], red[0][3]));
    m1 = fmaxf(fmaxf(red[1][0], red[1][1]), fmaxf(red[1][2], red[1][3]));

    float e0 = __expf(v0.x - m0) + __expf(v0.y - m0) + __expf(v0.z - m0) + __expf(v0.w - m0);
    float e1 = __expf(v1.x - m1) + __expf(v1.y - m1) + __expf(v1.z - m1) + __expf(v1.w - m1);
    e0 = wave_sum(e0); e1 = wave_sum(e1);
    if (lane == 0) { red[0][4 + wid] = e0; red[1][4 + wid] = e1; }
    __syncthreads();
    const float lse0 = m0 + __logf((red[0][4] + red[0][5]) + (red[0][6] + red[0][7]));
    const float lse1 = m1 + __logf((red[1][4] + red[1][5]) + (red[1][6] + red[1][7]));

    // state t: ext[t] = odd && t<S ? targets[t>>1] : blank(V-1)
    int ei = ((t & 1) && t < Sn) ? targets[b * Ln + (t >> 1)] : (Vn - 1);
    lp_ext[(size_t)r0 * 256 + t]       = __expf(rows[0][ei] - lse0);
    lp_ext[(size_t)(r0 + 1) * 256 + t] = __expf(rows[1][ei] - lse1);
}

// Kernel 2: CTC forward recursion in SCALED LINEAR space — no transcendentals.
// One wave per batch element; lane holds states 4*lane..4*lane+3 as mantissas
// m[4] with per-lane exponent E: alpha[s] = m[j] * 2^E. Renormalize every 4 steps.
// Dead lanes (all-zero mantissas) COPY the neighbor's pre-rescale E unchanged —
// no offset (the R3 "-64" offset compounded +24 bits per frontier lane -> inf).
__global__ __launch_bounds__(64) void ctc_kernel(const int* __restrict__ targets,
                                                 const float* __restrict__ lp_ext,
                                                 float* __restrict__ loss) {
    __shared__ float tile[2][TILE * 256];   // 64 KB exactly
    const int b    = blockIdx.x;
    const int lane = threadIdx.x;

    // skip flags (odd states only; even-register states never skip)
    bool sk1 = false, sk3 = false;
    {
        const int* tg = targets + b * Ln;
        int s1 = 4 * lane + 1, s3 = 4 * lane + 3;
        if (s1 >= 3 && s1 < Sn) sk1 = (tg[s1 >> 1] != tg[(s1 - 3) >> 1]);
        if (s3 >= 3 && s3 < Sn) sk3 = (tg[s3 >> 1] != tg[(s3 - 3) >> 1]);
    }
    // drain the targets loads so async16 is the only vmcnt source in the loop
    WAITVM0();

    const float* gb = lp_ext + (size_t)b * Tn * 256;
    #pragma unroll
    for (int u = 0; u < TILE; u++)
        async16(gb + (size_t)u * 256 + lane * 4, &tile[0][u * 256]);
    #pragma unroll
    for (int u = 0; u < TILE; u++)
        async16(gb + (size_t)(TILE + u) * 256 + lane * 4, &tile[1][u * 256]);

    // virtual alpha_{-1}: mass 1 at state 0 of lane 0; 1024 uniform steps follow.
    float m0 = (lane == 0) ? 1.0f : 0.0f, m1 = 0.f, m2 = 0.f, m3 = 0.f;
    int   E  = 0;     // per-lane scale: alpha = m * 2^E
    int   dE = 0;     // neighbor_E - E (constant between rescales)

    const int nt = Tn / TILE;   // 32 tiles

    auto consume_tile = [&](const float* cur) {
        #pragma unroll
        for (int u = 0; u < TILE; u++) {
            const float4 p = ((const float4*)(cur + u * 256))[lane];
            float pmm = __shfl_up(m3, 1);
            float pm1 = (lane == 0) ? 0.f : ldexpf(pmm, dE);  // align to local scale
            float n0 = (m0 + pm1) * p.x;                       // even s: no skip
            float n1 = (m1 + m0 + (sk1 ? pm1 : 0.f)) * p.y;
            float n2 = (m2 + m1) * p.z;                        // even s: no skip
            float n3 = (m3 + m2 + (sk3 ? m1 : 0.f)) * p.w;
            m0 = n0; m1 = n1; m2 = n2; m3 = n3;
            if ((u & 3) == 3) {   // rescale every 4 steps (p_min^4 ~ 2^-104: no flush)
                float mx = fmaxf(fmaxf(m0, m1), fmaxf(m2, m3));
                int k; frexpf(mx, &k);                  // mx==0 -> k=0
                int Enb_old = __shfl_up(E, 1);          // neighbor's pre-rescale E
                E = (mx > 0.f) ? (E + k) : Enb_old;     // dead lanes: copy, NO offset
                m0 = ldexpf(m0, -k); m1 = ldexpf(m1, -k);
                m2 = ldexpf(m2, -k); m3 = ldexpf(m3, -k);
                dE = __shfl_up(E, 1) - E;
            }
        }
    };

    for (int tb = 0; tb < nt - 1; tb++) {
        WAITVM32();                       // tile tb landed (tb+1 still in flight)
        const float* cur = tile[tb & 1];
        consume_tile(cur);
        if (tb + 2 < nt) {
            float* nxt = tile[tb & 1];
            const float* gn = gb + (size_t)(tb + 2) * TILE * 256;
            #pragma unroll
            for (int u = 0; u < TILE; u++)
                async16(gn + (size_t)u * 256 + lane * 4, &nxt[u * 256]);
        }
    }
    WAITVM0();                            // last tile
    consume_tile(tile[(nt - 1) & 1]);

    // alpha[200] = m0(lane50)*2^E50 ; alpha[199] = m3(lane49)*2^E49
    float q200 = __shfl(m0, 50); int E50 = __shfl(E, 50);
    float q199 = __shfl(m3, 49); int E49 = __shfl(E, 49);
    if (lane == 0) {
        float s = q200 + ldexpf(q199, E49 - E50);
        loss[b] = -LN2F * ((float)E50 + __log2f(s));
    }
}

// Kernel 3: mean over B losses -> scalar.
__global__ __launch_bounds__(64) void mean_kernel(const float* __restrict__ loss,
                                                  float* __restrict__ out) {
    int lane = threadIdx.x;
    float v = (lane < Bn) ? loss[lane] : 0.f;
    #pragma unroll
    for (int off = 32; off; off >>= 1) v += __shfl_xor(v, off);
    if (lane == 0) out[0] = v * (1.0f / Bn);
}

extern "C" void kernel_launch(void* const* d_in, const int* in_sizes, int n_in,
                              void* d_out, int out_size, void* d_ws, size_t ws_size,
                              hipStream_t stream) {
    const int*   targets = (const int*)d_in[0];
    const float* logits  = (const float*)d_in[1];

    // ws: lp_ext [B*T*256 floats = 33.55 MB] + loss[32]
    float* lp_ext = (float*)d_ws;
    float* loss   = (float*)((char*)d_ws + (size_t)Bn * Tn * 256 * sizeof(float) + 4096);

    pre_kernel<<<Bn * Tn / 2, 256, 0, stream>>>(targets, logits, lp_ext);
    ctc_kernel<<<Bn, 64, 0, stream>>>(targets, lp_ext, loss);
    mean_kernel<<<1, 64, 0, stream>>>(loss, (float*)d_out);
}

// Round 5
// 250.371 us; speedup vs baseline: 1.9501x; 1.0656x over previous
//
#include <hip/hip_runtime.h>
#include <math.h>

#define DEV static __device__ __forceinline__

constexpr int Bn = 32, Tn = 1024, Vn = 1024, Ln = 100, Sn = 2 * Ln + 1; // S=201
constexpr float LN2F = 0.6931471805599453f;
constexpr int   TILE = 32;          // timesteps per LDS tile (32 * 1 KB = 32 KB)

typedef const __attribute__((address_space(1))) unsigned int* as1_u32p;
typedef __attribute__((address_space(3))) unsigned int*       as3_u32p;

// async global->LDS DMA, 16 B per lane, lands at lds_base + lane*16 (wave-uniform base)
DEV void async16(const float* g, float* l) {
    __builtin_amdgcn_global_load_lds((as1_u32p)g, (as3_u32p)l, 16, 0, 0);
}
// explicit DMA-arrival fences (only async16 contributes vmcnt inside the K-loop)
#define WAITVM32() asm volatile("s_waitcnt vmcnt(32)" ::: "memory")
#define WAITVM0()  asm volatile("s_waitcnt vmcnt(0)"  ::: "memory")

// DPP wavefront shift-right by 1 (lane i <- lane i-1), VALU pipe — no LDS latency.
// dpp_ctrl 0x138 = WAVE_SHR1 (gfx9/CDNA). bound_ctrl=false -> lane 0 keeps `old`.
DEV float dpp_up1_f(float v) {                     // lane0 -> 0.0f
    return __builtin_bit_cast(float,
        __builtin_amdgcn_update_dpp(0, __builtin_bit_cast(int, v), 0x138, 0xf, 0xf, false));
}
DEV int dpp_up1_i(int v) {                         // lane0 -> own value (old = v)
    return __builtin_amdgcn_update_dpp(v, v, 0x138, 0xf, 0xf, false);
}

DEV float wave_max(float m) {
    #pragma unroll
    for (int off = 32; off; off >>= 1) m = fmaxf(m, __shfl_xor(m, off));
    return m;
}
DEV float wave_sum(float s) {
    #pragma unroll
    for (int off = 32; off; off >>= 1) s += __shfl_xor(s, off);
    return s;
}

// Kernel 1: two (b,t) rows per 256-thread block (2 independent loads -> MLP=2).
// Emits PROBABILITIES: lp_ext[row*256 + s] = exp(logits[row, ext[s]] - lse(row)).
__global__ __launch_bounds__(256) void pre_kernel(const int* __restrict__ targets,
                                                  const float* __restrict__ logits,
                                                  float* __restrict__ lp_ext) {
    __shared__ float rows[2][Vn];     // 8 KB
    __shared__ float red[2][8];
    const int t    = threadIdx.x;
    const int lane = t & 63;
    const int wid  = t >> 6;
    const int r0   = blockIdx.x * 2;      // rows r0, r0+1 share the same b (Tn even)
    const int b    = r0 >> 10;

    float4 v0 = ((const float4*)(logits + (size_t)r0 * Vn))[t];
    float4 v1 = ((const float4*)(logits + (size_t)(r0 + 1) * Vn))[t];
    ((float4*)rows[0])[t] = v0;
    ((float4*)rows[1])[t] = v1;

    float m0 = fmaxf(fmaxf(v0.x, v0.y), fmaxf(v0.z, v0.w));
    float m1 = fmaxf(fmaxf(v1.x, v1.y), fmaxf(v1.z, v1.w));
    m0 = wave_max(m0); m1 = wave_max(m1);
    if (lane == 0) { red[0][wid] = m0; red[1][wid] = m1; }
    __syncthreads();
    m0 = fmaxf(fmaxf(red[0][0], red[0][1]), fmaxf(red[0][2], red[0][3]));
    m1 = fmaxf(fmaxf(red[1][0], red[1][1]), fmaxf(red[1][2], red[1][3]));

    float e0 = __expf(v0.x - m0) + __expf(v0.y - m0) + __expf(v0.z - m0) + __expf(v0.w - m0);
    float e1 = __expf(v1.x - m1) + __expf(v1.y - m1) + __expf(v1.z - m1) + __expf(v1.w - m1);
    e0 = wave_sum(e0); e1 = wave_sum(e1);
    if (lane == 0) { red[0][4 + wid] = e0; red[1][4 + wid] = e1; }
    __syncthreads();
    const float lse0 = m0 + __logf((red[0][4] + red[0][5]) + (red[0][6] + red[0][7]));
    const float lse1 = m1 + __logf((red[1][4] + red[1][5]) + (red[1][6] + red[1][7]));

    // state t: ext[t] = odd && t<S ? targets[t>>1] : blank(V-1)
    int ei = ((t & 1) && t < Sn) ? targets[b * Ln + (t >> 1)] : (Vn - 1);
    lp_ext[(size_t)r0 * 256 + t]       = __expf(rows[0][ei] - lse0);
    lp_ext[(size_t)(r0 + 1) * 256 + t] = __expf(rows[1][ei] - lse1);
}

// Kernel 2: CTC forward recursion in SCALED LINEAR space — no transcendentals,
// no LDS-pipe cross-lane ops. One wave per batch element; lane holds states
// 4*lane..4*lane+3 as mantissas m[4] with per-lane exponent E (alpha = m*2^E).
// Cross-lane neighbor via DPP wave_shr:1. Renormalize every 4 steps; dead lanes
// copy the neighbor's pre-rescale E unchanged (R4-proven numerics).
__global__ __launch_bounds__(64) void ctc_kernel(const int* __restrict__ targets,
                                                 const float* __restrict__ lp_ext,
                                                 float* __restrict__ loss) {
    __shared__ float tile[2][TILE * 256];   // 64 KB exactly
    const int b    = blockIdx.x;
    const int lane = threadIdx.x;

    // skip flags (odd states only; even-register states never skip)
    bool sk1 = false, sk3 = false;
    {
        const int* tg = targets + b * Ln;
        int s1 = 4 * lane + 1, s3 = 4 * lane + 3;
        if (s1 >= 3 && s1 < Sn) sk1 = (tg[s1 >> 1] != tg[(s1 - 3) >> 1]);
        if (s3 >= 3 && s3 < Sn) sk3 = (tg[s3 >> 1] != tg[(s3 - 3) >> 1]);
    }
    // drain the targets loads so async16 is the only vmcnt source in the loop
    WAITVM0();

    const float* gb = lp_ext + (size_t)b * Tn * 256;
    #pragma unroll
    for (int u = 0; u < TILE; u++)
        async16(gb + (size_t)u * 256 + lane * 4, &tile[0][u * 256]);
    #pragma unroll
    for (int u = 0; u < TILE; u++)
        async16(gb + (size_t)(TILE + u) * 256 + lane * 4, &tile[1][u * 256]);

    // virtual alpha_{-1}: mass 1 at state 0 of lane 0; 1024 uniform steps follow.
    float m0 = (lane == 0) ? 1.0f : 0.0f, m1 = 0.f, m2 = 0.f, m3 = 0.f;
    int   E  = 0;     // per-lane scale: alpha = m * 2^E
    int   dE = 0;     // neighbor_E - E (constant between rescales)

    const int nt = Tn / TILE;   // 32 tiles

    auto consume_tile = [&](const float* cur) {
        #pragma unroll
        for (int u = 0; u < TILE; u++) {
            const float4 p = ((const float4*)(cur + u * 256))[lane];
            float pmm = dpp_up1_f(m3);                          // lane0 -> 0
            float pm1 = __builtin_amdgcn_ldexpf(pmm, dE);       // align to local scale
            float n0 = (m0 + pm1) * p.x;                        // even s: no skip
            float n1 = (m1 + m0 + (sk1 ? pm1 : 0.f)) * p.y;
            float n2 = (m2 + m1) * p.z;                         // even s: no skip
            float n3 = (m3 + m2 + (sk3 ? m1 : 0.f)) * p.w;
            m0 = n0; m1 = n1; m2 = n2; m3 = n3;
            if ((u & 3) == 3) {   // rescale every 4 steps (p_min^4 ~ 2^-104: no flush)
                float mx = fmaxf(fmaxf(m0, m1), fmaxf(m2, m3));
                int k = __builtin_amdgcn_frexp_expf(mx);        // mx==0 -> 0
                int Enb_old = dpp_up1_i(E);                     // neighbor pre-rescale E
                E = (mx > 0.f) ? (E + k) : Enb_old;             // dead lanes: copy, NO offset
                m0 = __builtin_amdgcn_ldexpf(m0, -k);
                m1 = __builtin_amdgcn_ldexpf(m1, -k);
                m2 = __builtin_amdgcn_ldexpf(m2, -k);
                m3 = __builtin_amdgcn_ldexpf(m3, -k);
                dE = dpp_up1_i(E) - E;
            }
        }
    };

    for (int tb = 0; tb < nt - 1; tb++) {
        WAITVM32();                       // tile tb landed (tb+1 still in flight)
        const float* cur = tile[tb & 1];
        consume_tile(cur);
        if (tb + 2 < nt) {
            float* nxt = tile[tb & 1];
            const float* gn = gb + (size_t)(tb + 2) * TILE * 256;
            #pragma unroll
            for (int u = 0; u < TILE; u++)
                async16(gn + (size_t)u * 256 + lane * 4, &nxt[u * 256]);
        }
    }
    WAITVM0();                            // last tile
    consume_tile(tile[(nt - 1) & 1]);

    // alpha[200] = m0(lane50)*2^E50 ; alpha[199] = m3(lane49)*2^E49
    float q200 = __shfl(m0, 50); int E50 = __shfl(E, 50);
    float q199 = __shfl(m3, 49); int E49 = __shfl(E, 49);
    if (lane == 0) {
        float s = q200 + __builtin_amdgcn_ldexpf(q199, E49 - E50);
        loss[b] = -LN2F * ((float)E50 + __log2f(s));
    }
}

// Kernel 3: mean over B losses -> scalar.
__global__ __launch_bounds__(64) void mean_kernel(const float* __restrict__ loss,
                                                  float* __restrict__ out) {
    int lane = threadIdx.x;
    float v = (lane < Bn) ? loss[lane] : 0.f;
    #pragma unroll
    for (int off = 32; off; off >>= 1) v += __shfl_xor(v, off);
    if (lane == 0) out[0] = v * (1.0f / Bn);
}

extern "C" void kernel_launch(void* const* d_in, const int* in_sizes, int n_in,
                              void* d_out, int out_size, void* d_ws, size_t ws_size,
                              hipStream_t stream) {
    const int*   targets = (const int*)d_in[0];
    const float* logits  = (const float*)d_in[1];

    // ws: lp_ext [B*T*256 floats = 33.55 MB] + loss[32]
    float* lp_ext = (float*)d_ws;
    float* loss   = (float*)((char*)d_ws + (size_t)Bn * Tn * 256 * sizeof(float) + 4096);

    pre_kernel<<<Bn * Tn / 2, 256, 0, stream>>>(targets, logits, lp_ext);
    ctc_kernel<<<Bn, 64, 0, stream>>>(targets, lp_ext, loss);
    mean_kernel<<<1, 64, 0, stream>>>(loss, (float*)d_out);
}

// Round 6
// 243.408 us; speedup vs baseline: 2.0059x; 1.0286x over previous
//
#include <hip/hip_runtime.h>
#include <math.h>

#define DEV static __device__ __forceinline__

constexpr int Bn = 32, Tn = 1024, Vn = 1024, Ln = 100, Sn = 2 * Ln + 1; // S=201
constexpr float LN2F = 0.6931471805599453f;
constexpr int   TILE = 32;          // timesteps per LDS tile (32 * 1 KB = 32 KB)

typedef const __attribute__((address_space(1))) unsigned int* as1_u32p;
typedef __attribute__((address_space(3))) unsigned int*       as3_u32p;

// async global->LDS DMA, 16 B per lane, lands at lds_base + lane*16 (wave-uniform base)
DEV void async16(const float* g, float* l) {
    __builtin_amdgcn_global_load_lds((as1_u32p)g, (as3_u32p)l, 16, 0, 0);
}
// explicit DMA-arrival fences (only async16 contributes vmcnt inside the K-loop)
#define WAITVM32() asm volatile("s_waitcnt vmcnt(32)" ::: "memory")
#define WAITVM0()  asm volatile("s_waitcnt vmcnt(0)"  ::: "memory")

// DPP wavefront shift-right by 1 (lane i <- lane i-1), VALU pipe — no LDS latency.
// dpp_ctrl 0x138 = WAVE_SHR1 (gfx9/CDNA). bound_ctrl=false -> lane 0 keeps `old`.
DEV float dpp_up1_f(float v) {                     // lane0 -> 0.0f
    return __builtin_bit_cast(float,
        __builtin_amdgcn_update_dpp(0, __builtin_bit_cast(int, v), 0x138, 0xf, 0xf, false));
}
DEV int dpp_up1_i(int v) {                         // lane0 -> own value (old = v)
    return __builtin_amdgcn_update_dpp(v, v, 0x138, 0xf, 0xf, false);
}

DEV float wave_max(float m) {
    #pragma unroll
    for (int off = 32; off; off >>= 1) m = fmaxf(m, __shfl_xor(m, off));
    return m;
}
DEV float wave_sum(float s) {
    #pragma unroll
    for (int off = 32; off; off >>= 1) s += __shfl_xor(s, off);
    return s;
}

// Kernel 1: two (b,t) rows per 256-thread block (2 independent loads -> MLP=2).
// Emits PROBABILITIES: lp_ext[row*256 + s] = exp(logits[row, ext[s]] - lse(row)).
__global__ __launch_bounds__(256) void pre_kernel(const int* __restrict__ targets,
                                                  const float* __restrict__ logits,
                                                  float* __restrict__ lp_ext) {
    __shared__ float rows[2][Vn];     // 8 KB
    __shared__ float red[2][8];
    const int t    = threadIdx.x;
    const int lane = t & 63;
    const int wid  = t >> 6;
    const int r0   = blockIdx.x * 2;      // rows r0, r0+1 share the same b (Tn even)
    const int b    = r0 >> 10;

    float4 v0 = ((const float4*)(logits + (size_t)r0 * Vn))[t];
    float4 v1 = ((const float4*)(logits + (size_t)(r0 + 1) * Vn))[t];
    ((float4*)rows[0])[t] = v0;
    ((float4*)rows[1])[t] = v1;

    float m0 = fmaxf(fmaxf(v0.x, v0.y), fmaxf(v0.z, v0.w));
    float m1 = fmaxf(fmaxf(v1.x, v1.y), fmaxf(v1.z, v1.w));
    m0 = wave_max(m0); m1 = wave_max(m1);
    if (lane == 0) { red[0][wid] = m0; red[1][wid] = m1; }
    __syncthreads();
    m0 = fmaxf(fmaxf(red[0][0], red[0][1]), fmaxf(red[0][2], red[0][3]));
    m1 = fmaxf(fmaxf(red[1][0], red[1][1]), fmaxf(red[1][2], red[1][3]));

    float e0 = __expf(v0.x - m0) + __expf(v0.y - m0) + __expf(v0.z - m0) + __expf(v0.w - m0);
    float e1 = __expf(v1.x - m1) + __expf(v1.y - m1) + __expf(v1.z - m1) + __expf(v1.w - m1);
    e0 = wave_sum(e0); e1 = wave_sum(e1);
    if (lane == 0) { red[0][4 + wid] = e0; red[1][4 + wid] = e1; }
    __syncthreads();
    const float lse0 = m0 + __logf((red[0][4] + red[0][5]) + (red[0][6] + red[0][7]));
    const float lse1 = m1 + __logf((red[1][4] + red[1][5]) + (red[1][6] + red[1][7]));

    // state t: ext[t] = odd && t<S ? targets[t>>1] : blank(V-1)
    int ei = ((t & 1) && t < Sn) ? targets[b * Ln + (t >> 1)] : (Vn - 1);
    lp_ext[(size_t)r0 * 256 + t]       = __expf(rows[0][ei] - lse0);
    lp_ext[(size_t)(r0 + 1) * 256 + t] = __expf(rows[1][ei] - lse1);
}

// Kernel 2: CTC forward recursion in SCALED LINEAR space — no transcendentals,
// no LDS-pipe cross-lane ops, whole-tile LDS reads hoisted into registers.
// 32 blocks x 1 wave on 256 CUs: occupancy is irrelevant -> __launch_bounds__(64,1)
// frees the full 512-VGPR budget so the 32x float4 tile buffer lives in registers
// (R5 post-mortem: 132-VGPR cap made the compiler sink ds_reads to uses,
// exposing ~120 cyc LDS latency per step).
__global__ __launch_bounds__(64, 1) void ctc_kernel(const int* __restrict__ targets,
                                                    const float* __restrict__ lp_ext,
                                                    float* __restrict__ loss) {
    __shared__ float tile[2][TILE * 256];   // 64 KB exactly
    const int b    = blockIdx.x;
    const int lane = threadIdx.x;

    // skip flags (odd states only; even-register states never skip) as {0,1} floats
    float sk1f = 0.f, sk3f = 0.f;
    {
        const int* tg = targets + b * Ln;
        int s1 = 4 * lane + 1, s3 = 4 * lane + 3;
        if (s1 >= 3 && s1 < Sn) sk1f = (tg[s1 >> 1] != tg[(s1 - 3) >> 1]) ? 1.f : 0.f;
        if (s3 >= 3 && s3 < Sn) sk3f = (tg[s3 >> 1] != tg[(s3 - 3) >> 1]) ? 1.f : 0.f;
    }
    // drain the targets loads so async16 is the only vmcnt source in the loop
    WAITVM0();

    const float* gb = lp_ext + (size_t)b * Tn * 256;
    #pragma unroll
    for (int u = 0; u < TILE; u++)
        async16(gb + (size_t)u * 256 + lane * 4, &tile[0][u * 256]);
    #pragma unroll
    for (int u = 0; u < TILE; u++)
        async16(gb + (size_t)(TILE + u) * 256 + lane * 4, &tile[1][u * 256]);

    // virtual alpha_{-1}: mass 1 at state 0 of lane 0; 1024 uniform steps follow.
    float m0 = (lane == 0) ? 1.0f : 0.0f, m1 = 0.f, m2 = 0.f, m3 = 0.f;
    int   E  = 0;     // per-lane scale: alpha = m * 2^E
    int   dE = 0;     // neighbor_E - E (constant between rescales)

    const int nt = Tn / TILE;   // 32 tiles

    auto consume_tile = [&](const float* cur) {
        // hoist the whole tile LDS->registers (128 VGPRs; budget is 512 at 1 wave/SIMD)
        float4 pr[TILE];
        #pragma unroll
        for (int u = 0; u < TILE; u++)
            pr[u] = ((const float4*)(cur + u * 256))[lane];
        #pragma unroll
        for (int u = 0; u < TILE; u++) {
            const float4 p = pr[u];
            float pmm = dpp_up1_f(m3);                          // lane0 -> 0
            float pm1 = __builtin_amdgcn_ldexpf(pmm, dE);       // align to local scale
            float n0 = (m0 + pm1) * p.x;                        // even s: no skip
            float n1 = fmaf(pm1, sk1f, m0 + m1) * p.y;
            float n2 = (m2 + m1) * p.z;                         // even s: no skip
            float n3 = fmaf(m1, sk3f, m2 + m3) * p.w;
            m0 = n0; m1 = n1; m2 = n2; m3 = n3;
            if ((u & 3) == 3) {   // rescale every 4 steps (p_min^4 ~ 2^-70: no flush)
                float mx = fmaxf(fmaxf(m0, m1), fmaxf(m2, m3));
                int k = __builtin_amdgcn_frexp_expf(mx);        // mx==0 -> 0
                int Enb_old = dpp_up1_i(E);                     // neighbor pre-rescale E
                E = (mx > 0.f) ? (E + k) : Enb_old;             // dead lanes: copy, NO offset
                m0 = __builtin_amdgcn_ldexpf(m0, -k);
                m1 = __builtin_amdgcn_ldexpf(m1, -k);
                m2 = __builtin_amdgcn_ldexpf(m2, -k);
                m3 = __builtin_amdgcn_ldexpf(m3, -k);
                dE = dpp_up1_i(E) - E;
            }
        }
    };

    for (int tb = 0; tb < nt - 1; tb++) {
        WAITVM32();                       // tile tb landed (tb+1 still in flight)
        const float* cur = tile[tb & 1];
        consume_tile(cur);
        if (tb + 2 < nt) {
            float* nxt = tile[tb & 1];
            const float* gn = gb + (size_t)(tb + 2) * TILE * 256;
            #pragma unroll
            for (int u = 0; u < TILE; u++)
                async16(gn + (size_t)u * 256 + lane * 4, &nxt[u * 256]);
        }
    }
    WAITVM0();                            // last tile
    consume_tile(tile[(nt - 1) & 1]);

    // alpha[200] = m0(lane50)*2^E50 ; alpha[199] = m3(lane49)*2^E49
    float q200 = __shfl(m0, 50); int E50 = __shfl(E, 50);
    float q199 = __shfl(m3, 49); int E49 = __shfl(E, 49);
    if (lane == 0) {
        float s = q200 + __builtin_amdgcn_ldexpf(q199, E49 - E50);
        loss[b] = -LN2F * ((float)E50 + __log2f(s));
    }
}

// Kernel 3: mean over B losses -> scalar.
__global__ __launch_bounds__(64) void mean_kernel(const float* __restrict__ loss,
                                                  float* __restrict__ out) {
    int lane = threadIdx.x;
    float v = (lane < Bn) ? loss[lane] : 0.f;
    #pragma unroll
    for (int off = 32; off; off >>= 1) v += __shfl_xor(v, off);
    if (lane == 0) out[0] = v * (1.0f / Bn);
}

extern "C" void kernel_launch(void* const* d_in, const int* in_sizes, int n_in,
                              void* d_out, int out_size, void* d_ws, size_t ws_size,
                              hipStream_t stream) {
    const int*   targets = (const int*)d_in[0];
    const float* logits  = (const float*)d_in[1];

    // ws: lp_ext [B*T*256 floats = 33.55 MB] + loss[32]
    float* lp_ext = (float*)d_ws;
    float* loss   = (float*)((char*)d_ws + (size_t)Bn * Tn * 256 * sizeof(float) + 4096);

    pre_kernel<<<Bn * Tn / 2, 256, 0, stream>>>(targets, logits, lp_ext);
    ctc_kernel<<<Bn, 64, 0, stream>>>(targets, lp_ext, loss);
    mean_kernel<<<1, 64, 0, stream>>>(loss, (float*)d_out);
}